// Round 1
// baseline (97.745 us; speedup 1.0000x reference)
//
#include <hip/hip_runtime.h>

// SelfAttention3D: B=2, C=64, N=8192 (8x32x32), QK=8.
// out = gamma * softmax(q.k) @ v + x, fused flash-style without max-tracking
// (energies bounded ~|8|, exp2 safe in fp32; softmax shift-invariance).
//
// ws layout: Qf bf16 (b,n,8) @0 (256KB) | Kf same @256KB | Vf bf16 MFMA-fragmentized @512KB (2MB)

using f32x16 = __attribute__((ext_vector_type(16))) float;
using u32x4  = __attribute__((ext_vector_type(4))) unsigned int;

#define LOG2E 1.4426950408889634f

static __device__ __forceinline__ f32x16 mfma_z(u32x4 a, u32x4 b) {
  f32x16 d;
  asm("v_mfma_f32_32x32x16_bf16 %0, %1, %2, 0" : "=v"(d) : "v"(a), "v"(b));
  return d;
}
static __device__ __forceinline__ void mfma_acc(f32x16& d, u32x4 a, u32x4 b) {
  asm("v_mfma_f32_32x32x16_bf16 %0, %1, %2, %0" : "+v"(d) : "v"(a), "v"(b));
}
static __device__ __forceinline__ unsigned pkbf(float lo, float hi) {
  unsigned r;
  asm("v_cvt_pk_bf16_f32 %0, %1, %2" : "=v"(r) : "v"(lo), "v"(hi));
  return r;
}
// exchanges hi-32-lanes of a with lo-32-lanes of b:
// a' = {a.lo, b.lo_old}, b' = {a.hi_old, b.hi}
static __device__ __forceinline__ void plswap(unsigned& a, unsigned& b) {
  asm("v_permlane32_swap_b32 %0, %1" : "+v"(a), "+v"(b));
}
static __device__ __forceinline__ unsigned f2bf(float f) {
  union { float f; unsigned u; } v; v.f = f;
  return (v.u + 0x7fffu + ((v.u >> 16) & 1u)) >> 16;  // RNE (no NaNs here)
}
static __device__ __forceinline__ u32x4 pack8(const float* p) {
  u32x4 r;
  r[0] = f2bf(p[0]) | (f2bf(p[1]) << 16);
  r[1] = f2bf(p[2]) | (f2bf(p[3]) << 16);
  r[2] = f2bf(p[4]) | (f2bf(p[5]) << 16);
  r[3] = f2bf(p[6]) | (f2bf(p[7]) << 16);
  return r;
}

// ---- P1: q/k projections. grid 256 = b*128 + nb, block 128 (2 waves).
// lane: ql = n-offset (32), ch = channel-half; shfl_xor(32) reduce.
__global__ __launch_bounds__(128) void k_proj_qk(
    const float* __restrict__ x, const float* __restrict__ Wq, const float* __restrict__ bq,
    const float* __restrict__ Wk, const float* __restrict__ bk,
    u32x4* __restrict__ Qf, u32x4* __restrict__ Kf) {
  __shared__ float sW[2][8][64];
  __shared__ float sb[2][8];
  const int tid = threadIdx.x;
  {
    float* w = &sW[0][0][0];
    for (int i = tid; i < 512; i += 128) { w[i] = Wq[i]; w[512 + i] = Wk[i]; }
    if (tid < 8) { sb[0][tid] = bq[tid]; sb[1][tid] = bk[tid]; }
  }
  __syncthreads();
  const int b    = blockIdx.x >> 7;
  const int nb   = blockIdx.x & 127;
  const int lane = tid & 63;
  const int wv   = tid >> 6;
  const int ql   = lane & 31, ch = lane >> 5;
  const int n    = nb * 64 + wv * 32 + ql;
  const float* xp = x + ((size_t)b << 19) + n;
  float aq[8], ak[8];
  #pragma unroll
  for (int o = 0; o < 8; ++o) { aq[o] = 0.f; ak[o] = 0.f; }
  #pragma unroll
  for (int ci = 0; ci < 32; ci += 4) {
    const int c = ch * 32 + ci;
    float xv[4];
    #pragma unroll
    for (int j = 0; j < 4; ++j) xv[j] = xp[(size_t)(c + j) << 13];
    #pragma unroll
    for (int o = 0; o < 8; ++o) {
      const float4 wq = *(const float4*)&sW[0][o][c];
      const float4 wk = *(const float4*)&sW[1][o][c];
      aq[o] += wq.x * xv[0] + wq.y * xv[1] + wq.z * xv[2] + wq.w * xv[3];
      ak[o] += wk.x * xv[0] + wk.y * xv[1] + wk.z * xv[2] + wk.w * xv[3];
    }
  }
  #pragma unroll
  for (int o = 0; o < 8; ++o) {
    aq[o] += __shfl_xor(aq[o], 32, 64);
    ak[o] += __shfl_xor(ak[o], 32, 64);
  }
  if (ch == 0) {
    float q8[8], k8[8];
    #pragma unroll
    for (int o = 0; o < 8; ++o) {
      q8[o] = (aq[o] + sb[0][o]) * LOG2E;  // fold log2(e) into Q so P = exp2(S)
      k8[o] = ak[o] + sb[1][o];
    }
    Qf[((size_t)b << 13) + n] = pack8(q8);
    Kf[((size_t)b << 13) + n] = pack8(k8);
  }
}

// ---- P2: v projection, writes V pre-fragmentized for 32x32x16 MFMA.
// Fragment unit (16B): (b, blk16 = n>>4, ct = c>>5) -> 64 lanes, lane = ((n>>3)&1)*32 + (c&31),
// bytes e = n&7. grid 256 = b*128 + coq*8 + ngc, block 128; thread = 4 channels x 8 positions.
__global__ __launch_bounds__(128) void k_proj_v(
    const float* __restrict__ x, const float* __restrict__ Wv, const float* __restrict__ bv,
    u32x4* __restrict__ Vf) {
  const int bid = blockIdx.x;
  const int b   = bid >> 7;
  const int coq = (bid >> 3) & 15;
  const int ngc = bid & 7;
  const int ng  = ngc * 128 + threadIdx.x;  // 0..1023, 8 positions each
  const int co  = coq * 4;
  float acc[4][8];
  #pragma unroll
  for (int i = 0; i < 4; ++i)
    #pragma unroll
    for (int e = 0; e < 8; ++e) acc[i][e] = 0.f;
  const float* xb = x + ((size_t)b << 19) + ((size_t)ng << 3);
  for (int c = 0; c < 64; ++c) {
    const float4* xp = (const float4*)(xb + ((size_t)c << 13));
    const float4 x0 = xp[0];
    const float4 x1 = xp[1];
    #pragma unroll
    for (int i = 0; i < 4; ++i) {
      const float wv = Wv[(co + i) * 64 + c];
      acc[i][0] += wv * x0.x; acc[i][1] += wv * x0.y;
      acc[i][2] += wv * x0.z; acc[i][3] += wv * x0.w;
      acc[i][4] += wv * x1.x; acc[i][5] += wv * x1.y;
      acc[i][6] += wv * x1.z; acc[i][7] += wv * x1.w;
    }
  }
  #pragma unroll
  for (int i = 0; i < 4; ++i) {
    const int c = co + i;
    const float bias = bv[c];
    float v8[8];
    #pragma unroll
    for (int e = 0; e < 8; ++e) v8[e] = acc[i][e] + bias;
    const int idx = ((b * 512 + (ng >> 1)) * 2 + (c >> 5)) * 64 + (ng & 1) * 32 + (c & 31);
    Vf[idx] = pack8(v8);
  }
}

// ---- fused attention. grid 256 = b*128 + qb (64 queries per block),
// block 512 = 8 waves = 8 key-chunks of 1024. No barriers in main loop.
// Wave: 64 q (2 x 32-tiles) x 64 c in regs (64 VGPR acc). Per 32-key iter:
//   S^T = mfma(K, Q^T) (kd 8->16 zero-pad via zero upper lanes)
//   P = exp2(S^T) (no max subtraction), l += rowsum
//   cvt_pk -> bf16 words, permlane32_swap -> PV fragments (in-register)
//   O^T += mfma(V^T, P^T) so epilogue writes coalesce along N.
// Merge 8 chunk-partials with LDS ds_add_f32, epilogue: gamma*O/l + x.
__global__ __launch_bounds__(512, 2) void k_attn(
    const u32x4* __restrict__ Qf, const u32x4* __restrict__ Kf, const u32x4* __restrict__ Vf,
    const float* __restrict__ x, const float* __restrict__ gamma, float* __restrict__ out) {
  __shared__ float sO[64 * 64];
  __shared__ float sl[64];
  const int tid  = threadIdx.x;
  const int b    = blockIdx.x >> 7;
  const int qb   = blockIdx.x & 127;
  const int i0   = qb * 64;
  const int w    = tid >> 6;
  const int lane = tid & 63;
  const int ql   = lane & 31;
  const int h    = lane >> 5;

  for (int i = tid; i < 64 * 64; i += 512) sO[i] = 0.f;
  if (tid < 64) sl[tid] = 0.f;
  __syncthreads();

  u32x4 zer; zer[0] = 0u; zer[1] = 0u; zer[2] = 0u; zer[3] = 0u;
  const int qkbase = b * 8192;
  const u32x4 qf0 = (lane < 32) ? Qf[qkbase + i0 + lane] : zer;        // kd 8..15 = 0
  const u32x4 qf1 = (lane < 32) ? Qf[qkbase + i0 + 32 + lane] : zer;

  f32x16 accO[2][2];
  #pragma unroll
  for (int t = 0; t < 2; ++t)
    #pragma unroll
    for (int ct = 0; ct < 2; ++ct)
      #pragma unroll
      for (int r = 0; r < 16; ++r) accO[t][ct][r] = 0.f;
  float lacc[2] = {0.f, 0.f};

  #pragma unroll 2
  for (int it = 0; it < 32; ++it) {
    const int j0 = w * 1024 + it * 32;
    const u32x4 kf = (lane < 32) ? Kf[qkbase + j0 + lane] : zer;
    u32x4 vf[2][2];
    #pragma unroll
    for (int s = 0; s < 2; ++s)
      #pragma unroll
      for (int ct = 0; ct < 2; ++ct)
        vf[s][ct] = Vf[((b * 512 + (j0 >> 4) + s) * 2 + ct) * 64 + lane];

    #pragma unroll
    for (int t = 0; t < 2; ++t) {
      const u32x4 qf = t ? qf1 : qf0;
      // S^T[j][q]: lane q=ql, reg r -> j = (r&3) + 8*(r>>2) + 4*h
      f32x16 sacc = mfma_z(kf, qf);
      float p[16];
      #pragma unroll
      for (int r = 0; r < 16; ++r) p[r] = __builtin_exp2f(sacc[r]);
      lacc[t] += (((p[0] + p[1]) + (p[2] + p[3])) + ((p[4] + p[5]) + (p[6] + p[7])))
               + (((p[8] + p[9]) + (p[10] + p[11])) + ((p[12] + p[13]) + (p[14] + p[15])));
      // words wd[q'][m] = bf16 pair at j = 4h + 8q' + 2m (+1)
      unsigned wd[4][2];
      #pragma unroll
      for (int qq = 0; qq < 4; ++qq) {
        wd[qq][0] = pkbf(p[4 * qq + 0], p[4 * qq + 1]);
        wd[qq][1] = pkbf(p[4 * qq + 2], p[4 * qq + 3]);
      }
      // redistribute: fragment lane (q, h) needs j = kstep*16 + 8h + e
      plswap(wd[0][0], wd[1][0]);  // -> frag0 word0, word2
      plswap(wd[0][1], wd[1][1]);  // -> frag0 word1, word3
      plswap(wd[2][0], wd[3][0]);  // -> frag1 word0, word2
      plswap(wd[2][1], wd[3][1]);  // -> frag1 word1, word3
      u32x4 pf0, pf1;
      pf0[0] = wd[0][0]; pf0[1] = wd[0][1]; pf0[2] = wd[1][0]; pf0[3] = wd[1][1];
      pf1[0] = wd[2][0]; pf1[1] = wd[2][1]; pf1[2] = wd[3][0]; pf1[3] = wd[3][1];
      #pragma unroll
      for (int ct = 0; ct < 2; ++ct) {
        mfma_acc(accO[t][ct], vf[0][ct], pf0);   // O^T = V^T * P^T
        mfma_acc(accO[t][ct], vf[1][ct], pf1);
      }
    }
  }

  // merge the 8 key-chunk partials
  #pragma unroll
  for (int t = 0; t < 2; ++t) {
    #pragma unroll
    for (int ct = 0; ct < 2; ++ct)
      #pragma unroll
      for (int r = 0; r < 16; ++r) {
        const int crow = ct * 32 + (r & 3) + 8 * (r >> 2) + 4 * h;
        atomicAdd(&sO[crow * 64 + t * 32 + ql], accO[t][ct][r]);
      }
    atomicAdd(&sl[t * 32 + ql], lacc[t]);
  }
  __syncthreads();

  const float g  = gamma[0];
  const int   c  = tid >> 3;
  const int   qg = (tid & 7) * 8;
  const size_t base = (((size_t)b * 64 + c) << 13) + i0 + qg;
  #pragma unroll
  for (int e = 0; e < 8; ++e) {
    const float ov = sO[c * 64 + qg + e] / sl[qg + e];
    out[base + e] = g * ov + x[base + e];
  }
}

extern "C" void kernel_launch(void* const* d_in, const int* in_sizes, int n_in,
                              void* d_out, int out_size, void* d_ws, size_t ws_size,
                              hipStream_t stream) {
  const float* x  = (const float*)d_in[0];
  const float* Wq = (const float*)d_in[1];
  const float* bq = (const float*)d_in[2];
  const float* Wk = (const float*)d_in[3];
  const float* bk = (const float*)d_in[4];
  const float* Wv = (const float*)d_in[5];
  const float* bv = (const float*)d_in[6];
  const float* gm = (const float*)d_in[7];
  if (ws_size < 2621440u) return;  // need 2.5 MiB scratch
  char* ws = (char*)d_ws;
  u32x4* Qf = (u32x4*)(ws);
  u32x4* Kf = (u32x4*)(ws + (256 << 10));
  u32x4* Vf = (u32x4*)(ws + (512 << 10));
  float* out = (float*)d_out;

  k_proj_qk<<<dim3(256), dim3(128), 0, stream>>>(x, Wq, bq, Wk, bk, Qf, Kf);
  k_proj_v <<<dim3(256), dim3(128), 0, stream>>>(x, Wv, bv, Vf);
  k_attn   <<<dim3(256), dim3(512), 0, stream>>>(Qf, Kf, Vf, x, gm, out);
}

// Round 2
// 79.146 us; speedup vs baseline: 1.2350x; 1.2350x over previous
//
#include <hip/hip_runtime.h>

// SelfAttention3D: B=2, C=64, N=8192 (8x32x32), QK=8.
// out = gamma * softmax(q.k) @ v + x, fused flash-style without max-tracking
// (energies bounded ~|8|, exp2 safe in fp32; softmax shift-invariance).
//
// ws layout: Qf bf16 (b,n,8) @0 (256KB) | Kf same @256KB | Vf bf16 MFMA-fragmentized @512KB (2MB)

using f32x16 = __attribute__((ext_vector_type(16))) float;
using u32x4  = __attribute__((ext_vector_type(4))) unsigned int;

#define LOG2E 1.4426950408889634f

static __device__ __forceinline__ f32x16 mfma_z(u32x4 a, u32x4 b) {
  f32x16 d;
  asm("v_mfma_f32_32x32x16_bf16 %0, %1, %2, 0" : "=v"(d) : "v"(a), "v"(b));
  return d;
}
static __device__ __forceinline__ void mfma_acc(f32x16& d, u32x4 a, u32x4 b) {
  asm("v_mfma_f32_32x32x16_bf16 %0, %1, %2, %0" : "+v"(d) : "v"(a), "v"(b));
}
static __device__ __forceinline__ unsigned pkbf(float lo, float hi) {
  unsigned r;
  asm("v_cvt_pk_bf16_f32 %0, %1, %2" : "=v"(r) : "v"(lo), "v"(hi));
  return r;
}
// exchanges hi-32-lanes of a with lo-32-lanes of b
static __device__ __forceinline__ void plswap(unsigned& a, unsigned& b) {
  asm("v_permlane32_swap_b32 %0, %1" : "+v"(a), "+v"(b));
}
static __device__ __forceinline__ unsigned f2bf(float f) {
  union { float f; unsigned u; } v; v.f = f;
  return (v.u + 0x7fffu + ((v.u >> 16) & 1u)) >> 16;  // RNE (no NaNs here)
}
static __device__ __forceinline__ u32x4 pack8(const float* p) {
  u32x4 r;
  r[0] = f2bf(p[0]) | (f2bf(p[1]) << 16);
  r[1] = f2bf(p[2]) | (f2bf(p[3]) << 16);
  r[2] = f2bf(p[4]) | (f2bf(p[5]) << 16);
  r[3] = f2bf(p[6]) | (f2bf(p[7]) << 16);
  return r;
}

// ---- fused projections: blocks [0,256) do q/k, blocks [256,768) do v.
__global__ __launch_bounds__(128) void k_proj(
    const float* __restrict__ x,
    const float* __restrict__ Wq, const float* __restrict__ bq,
    const float* __restrict__ Wk, const float* __restrict__ bk,
    const float* __restrict__ Wv, const float* __restrict__ bv,
    u32x4* __restrict__ Qf, u32x4* __restrict__ Kf, u32x4* __restrict__ Vf) {
  __shared__ float sW[2][8][64];
  __shared__ float sb[2][8];
  const int tid = threadIdx.x;
  if (blockIdx.x < 256) {
    // ---- q/k projection: grid 256 = b*128 + nb, 2 waves, shfl_xor(32) c-reduce
    {
      float* wp = &sW[0][0][0];
      for (int i = tid; i < 512; i += 128) { wp[i] = Wq[i]; wp[512 + i] = Wk[i]; }
      if (tid < 8) { sb[0][tid] = bq[tid]; sb[1][tid] = bk[tid]; }
    }
    __syncthreads();
    const int b    = blockIdx.x >> 7;
    const int nb   = blockIdx.x & 127;
    const int lane = tid & 63;
    const int wv   = tid >> 6;
    const int ql   = lane & 31, ch = lane >> 5;
    const int n    = nb * 64 + wv * 32 + ql;
    const float* xp = x + ((size_t)b << 19) + n;
    float aq[8], ak[8];
    #pragma unroll
    for (int o = 0; o < 8; ++o) { aq[o] = 0.f; ak[o] = 0.f; }
    #pragma unroll
    for (int ci = 0; ci < 32; ci += 4) {
      const int c = ch * 32 + ci;
      float xv[4];
      #pragma unroll
      for (int j = 0; j < 4; ++j) xv[j] = xp[(size_t)(c + j) << 13];
      #pragma unroll
      for (int o = 0; o < 8; ++o) {
        const float4 wq = *(const float4*)&sW[0][o][c];
        const float4 wk = *(const float4*)&sW[1][o][c];
        aq[o] += wq.x * xv[0] + wq.y * xv[1] + wq.z * xv[2] + wq.w * xv[3];
        ak[o] += wk.x * xv[0] + wk.y * xv[1] + wk.z * xv[2] + wk.w * xv[3];
      }
    }
    #pragma unroll
    for (int o = 0; o < 8; ++o) {
      aq[o] += __shfl_xor(aq[o], 32, 64);
      ak[o] += __shfl_xor(ak[o], 32, 64);
    }
    if (ch == 0) {
      float q8[8], k8[8];
      #pragma unroll
      for (int o = 0; o < 8; ++o) {
        q8[o] = (aq[o] + sb[0][o]) * LOG2E;  // fold log2(e) so P = exp2(S)
        k8[o] = ak[o] + sb[1][o];
      }
      Qf[((size_t)b << 13) + n] = pack8(q8);
      Kf[((size_t)b << 13) + n] = pack8(k8);
    }
  } else {
    // ---- v projection, pre-fragmentized for 32x32x16 MFMA.
    // Fragment (16B): (b, n>>4, c>>5) -> lane = ((n>>3)&1)*32 + (c&31), bytes = n&7.
    // grid 512 = b*256 + coq*8 + ngc; thread = 2 channels x 8 positions.
    const int bid = blockIdx.x - 256;
    const int b   = bid >> 8;
    const int coq = (bid >> 3) & 31;
    const int ngc = bid & 7;
    const int ng  = ngc * 128 + tid;       // 0..1023, 8 positions each
    const int co  = coq * 2;
    float acc[2][8];
    #pragma unroll
    for (int i = 0; i < 2; ++i)
      #pragma unroll
      for (int e = 0; e < 8; ++e) acc[i][e] = 0.f;
    const float* xb = x + ((size_t)b << 19) + ((size_t)ng << 3);
    for (int c = 0; c < 64; ++c) {
      const float4* xp = (const float4*)(xb + ((size_t)c << 13));
      const float4 x0 = xp[0];
      const float4 x1 = xp[1];
      #pragma unroll
      for (int i = 0; i < 2; ++i) {
        const float wv = Wv[(co + i) * 64 + c];
        acc[i][0] += wv * x0.x; acc[i][1] += wv * x0.y;
        acc[i][2] += wv * x0.z; acc[i][3] += wv * x0.w;
        acc[i][4] += wv * x1.x; acc[i][5] += wv * x1.y;
        acc[i][6] += wv * x1.z; acc[i][7] += wv * x1.w;
      }
    }
    #pragma unroll
    for (int i = 0; i < 2; ++i) {
      const int c = co + i;
      const float bias = bv[c];
      float v8[8];
      #pragma unroll
      for (int e = 0; e < 8; ++e) v8[e] = acc[i][e] + bias;
      const int idx = ((b * 512 + (ng >> 1)) * 2 + (c >> 5)) * 64 + (ng & 1) * 32 + (c & 31);
      Vf[idx] = pack8(v8);
    }
  }
}

// ---- fused attention. grid 512 = b*256 + qb (32 queries per block),
// block 512 = 8 waves = 8 key-chunks of 1024. No barriers in main loop.
// Wave: 32 q x 64 c in regs (32 VGPR acc), software-pipelined K/V loads
// (manual 2x unroll, named A/B buffers). Per 32-key iter:
//   S^T = mfma(K, Q^T); P = exp2(S^T); l += rowsum(P)
//   cvt_pk -> bf16, permlane32_swap -> PV fragments in-register
//   O^T += mfma(V^T, P^T)
// Merge 8 chunk-partials via LDS atomics; epilogue gamma*O/l + x (float4).
__global__ __launch_bounds__(512, 4) void k_attn(
    const u32x4* __restrict__ Qf, const u32x4* __restrict__ Kf, const u32x4* __restrict__ Vf,
    const float* __restrict__ x, const float* __restrict__ gamma, float* __restrict__ out) {
  __shared__ float sO[64][33];   // [c][q], padded vs bank conflicts
  __shared__ float sl[32];
  const int tid  = threadIdx.x;
  const int b    = blockIdx.x >> 8;
  const int qb   = blockIdx.x & 255;
  const int i0   = qb * 32;
  const int w    = tid >> 6;
  const int lane = tid & 63;
  const int ql   = lane & 31;
  const int h    = lane >> 5;

  for (int i = tid; i < 64 * 33; i += 512) (&sO[0][0])[i] = 0.f;
  if (tid < 32) sl[tid] = 0.f;
  __syncthreads();

  u32x4 zer; zer[0] = 0u; zer[1] = 0u; zer[2] = 0u; zer[3] = 0u;
  const int qkbase = b * 8192;
  const u32x4 qf = (lane < 32) ? Qf[qkbase + i0 + lane] : zer;  // kd 8..15 = 0

  f32x16 acc0, acc1;
  #pragma unroll
  for (int r = 0; r < 16; ++r) { acc0[r] = 0.f; acc1[r] = 0.f; }
  float lacc = 0.f;

  const int jbase = qkbase + w * 1024;
  const u32x4* __restrict__ vbase = Vf + ((size_t)(b * 512 + w * 64) << 7) + lane;

  auto body = [&](const u32x4& kf, const u32x4* vf) {
    // S^T[j][q]: lane q=ql, reg r -> j = (r&3) + 8*(r>>2) + 4*h
    f32x16 sacc = mfma_z(kf, qf);
    float p[16];
    #pragma unroll
    for (int r = 0; r < 16; ++r) p[r] = __builtin_exp2f(sacc[r]);
    lacc += (((p[0] + p[1]) + (p[2] + p[3])) + ((p[4] + p[5]) + (p[6] + p[7])))
          + (((p[8] + p[9]) + (p[10] + p[11])) + ((p[12] + p[13]) + (p[14] + p[15])));
    unsigned wd[4][2];
    #pragma unroll
    for (int qq = 0; qq < 4; ++qq) {
      wd[qq][0] = pkbf(p[4 * qq + 0], p[4 * qq + 1]);
      wd[qq][1] = pkbf(p[4 * qq + 2], p[4 * qq + 3]);
    }
    plswap(wd[0][0], wd[1][0]);
    plswap(wd[0][1], wd[1][1]);
    plswap(wd[2][0], wd[3][0]);
    plswap(wd[2][1], wd[3][1]);
    u32x4 pf0, pf1;
    pf0[0] = wd[0][0]; pf0[1] = wd[0][1]; pf0[2] = wd[1][0]; pf0[3] = wd[1][1];
    pf1[0] = wd[2][0]; pf1[1] = wd[2][1]; pf1[2] = wd[3][0]; pf1[3] = wd[3][1];
    mfma_acc(acc0, vf[0], pf0);   // O^T = V^T * P^T, channels 0..31
    mfma_acc(acc1, vf[1], pf0);   // channels 32..63
    mfma_acc(acc0, vf[2], pf1);
    mfma_acc(acc1, vf[3], pf1);
  };

  u32x4 kA, kB, vA[4], vB[4];
  kA = (lane < 32) ? Kf[jbase + lane] : zer;
  { const u32x4* vp = vbase;
    vA[0] = vp[0]; vA[1] = vp[64]; vA[2] = vp[128]; vA[3] = vp[192]; }
  #pragma unroll 1
  for (int it = 0; it < 32; it += 2) {
    kB = (lane < 32) ? Kf[jbase + (it + 1) * 32 + lane] : zer;
    { const u32x4* vp = vbase + (size_t)(it + 1) * 256;
      vB[0] = vp[0]; vB[1] = vp[64]; vB[2] = vp[128]; vB[3] = vp[192]; }
    body(kA, vA);
    const int n2 = (it + 2) & 31;  // tail prefetch wraps (harmless)
    kA = (lane < 32) ? Kf[jbase + n2 * 32 + lane] : zer;
    { const u32x4* vp = vbase + (size_t)n2 * 256;
      vA[0] = vp[0]; vA[1] = vp[64]; vA[2] = vp[128]; vA[3] = vp[192]; }
    body(kB, vB);
  }

  // merge the 8 key-chunk partials
  #pragma unroll
  for (int r = 0; r < 16; ++r) {
    const int cr = (r & 3) + 8 * (r >> 2) + 4 * h;
    atomicAdd(&sO[cr][ql], acc0[r]);
    atomicAdd(&sO[cr + 32][ql], acc1[r]);
  }
  atomicAdd(&sl[ql], lacc);
  __syncthreads();

  const float g  = gamma[0];
  const int   c  = tid >> 3;
  const int   qg = (tid & 7) * 4;
  const size_t base = (((size_t)b * 64 + c) << 13) + i0 + qg;
  const float4 xv = *(const float4*)&x[base];
  float4 o;
  o.x = g * (sO[c][qg + 0] / sl[qg + 0]) + xv.x;
  o.y = g * (sO[c][qg + 1] / sl[qg + 1]) + xv.y;
  o.z = g * (sO[c][qg + 2] / sl[qg + 2]) + xv.z;
  o.w = g * (sO[c][qg + 3] / sl[qg + 3]) + xv.w;
  *(float4*)&out[base] = o;
}

extern "C" void kernel_launch(void* const* d_in, const int* in_sizes, int n_in,
                              void* d_out, int out_size, void* d_ws, size_t ws_size,
                              hipStream_t stream) {
  const float* x  = (const float*)d_in[0];
  const float* Wq = (const float*)d_in[1];
  const float* bq = (const float*)d_in[2];
  const float* Wk = (const float*)d_in[3];
  const float* bk = (const float*)d_in[4];
  const float* Wv = (const float*)d_in[5];
  const float* bv = (const float*)d_in[6];
  const float* gm = (const float*)d_in[7];
  if (ws_size < 2621440u) return;  // need 2.5 MiB scratch
  char* ws = (char*)d_ws;
  u32x4* Qf = (u32x4*)(ws);
  u32x4* Kf = (u32x4*)(ws + (256 << 10));
  u32x4* Vf = (u32x4*)(ws + (512 << 10));
  float* out = (float*)d_out;

  k_proj<<<dim3(768), dim3(128), 0, stream>>>(x, Wq, bq, Wk, bk, Wv, bv, Qf, Kf, Vf);
  k_attn<<<dim3(512), dim3(512), 0, stream>>>(Qf, Kf, Vf, x, gm, out);
}